// Round 1
// baseline (1784.021 us; speedup 1.0000x reference)
//
#include <hip/hip_runtime.h>
#include <cstdint>
#include <cstddef>

// Problem constants (from reference)
#define NBATCH   8192
#define DFEAT    256
#define DRAW     256
#define DCONV    128
#define DEMB     256
#define NCLASS   5
#define NEDGE    500000
#define BN_EPS   1e-3f

// ============================================================================
// Generic fp32 tiled GEMM core: C[M,N] = epi( A(gathered rows) @ B )
// block = 256 threads, tile 64x64, K-step 16, per-thread 4x4.
// Requires M%64==0, N%64==0, K%16==0 (true for all shapes here).
// Epilogue: optional bias[n], optional BN (packed rows gamma/beta/mean/var,
// leading dim bn_ld), optional accumulate (+= C), optional relu.
// ============================================================================
__device__ __forceinline__ void gemm_core(
    const float* __restrict__ A, int lda, const int* __restrict__ gather,
    const float* __restrict__ B, int ldb,
    float* __restrict__ C, int ldc,
    int K,
    const float* __restrict__ bias,
    const float* __restrict__ bn, int bn_ld,
    int accumulate, int relu,
    int tileM, int tileN)
{
    __shared__ float As[16][64];
    __shared__ float Bs[16][64];
    const int t  = threadIdx.x;
    const int mL = t >> 2;          // 0..63  : A-load row within tile
    const int k4 = (t & 3) * 4;     // 0,4,8,12 : A-load k base (float4)
    const int nL = t & 63;          // B-load col within tile
    const int kB = (t >> 6) * 4;    // 0,4,8,12 : B-load k base
    const int m0 = (t & 15) * 4;    // compute: 4 rows
    const int n0 = (t >> 4) * 4;    // compute: 4 cols

    const int arow = gather ? gather[tileM + mL] : (tileM + mL);
    const float* Arow = A + (size_t)arow * lda;

    float acc[4][4] = {};

    for (int k0 = 0; k0 < K; k0 += 16) {
        float4 av = *(const float4*)(Arow + k0 + k4);
        As[k4 + 0][mL] = av.x;
        As[k4 + 1][mL] = av.y;
        As[k4 + 2][mL] = av.z;
        As[k4 + 3][mL] = av.w;
        #pragma unroll
        for (int i = 0; i < 4; ++i)
            Bs[kB + i][nL] = B[(size_t)(k0 + kB + i) * ldb + tileN + nL];
        __syncthreads();
        #pragma unroll
        for (int k = 0; k < 16; ++k) {
            float4 a = *(const float4*)&As[k][m0];
            float4 b = *(const float4*)&Bs[k][n0];
            acc[0][0] += a.x * b.x; acc[0][1] += a.x * b.y; acc[0][2] += a.x * b.z; acc[0][3] += a.x * b.w;
            acc[1][0] += a.y * b.x; acc[1][1] += a.y * b.y; acc[1][2] += a.y * b.z; acc[1][3] += a.y * b.w;
            acc[2][0] += a.z * b.x; acc[2][1] += a.z * b.y; acc[2][2] += a.z * b.z; acc[2][3] += a.z * b.w;
            acc[3][0] += a.w * b.x; acc[3][1] += a.w * b.y; acc[3][2] += a.w * b.z; acc[3][3] += a.w * b.w;
        }
        __syncthreads();
    }

    #pragma unroll
    for (int i = 0; i < 4; ++i) {
        int row  = tileM + m0 + i;
        int col0 = tileN + n0;
        float* cp = C + (size_t)row * ldc + col0;
        float vv[4] = {acc[i][0], acc[i][1], acc[i][2], acc[i][3]};
        #pragma unroll
        for (int j = 0; j < 4; ++j) {
            int c = col0 + j;
            float x = vv[j];
            if (bias) x += bias[c];
            if (bn) {
                float g  = bn[c];
                float be = bn[bn_ld + c];
                float mu = bn[2 * bn_ld + c];
                float va = bn[3 * bn_ld + c];
                x = g * (x - mu) * rsqrtf(va + BN_EPS) + be;
            }
            if (accumulate) x += cp[j];
            if (relu) x = fmaxf(x, 0.0f);
            vv[j] = x;
        }
        *(float4*)cp = make_float4(vv[0], vv[1], vv[2], vv[3]);
    }
}

__global__ __launch_bounds__(256) void gemm_plain(
    const float* __restrict__ A, int lda, const int* __restrict__ gather,
    const float* __restrict__ B, int ldb,
    float* __restrict__ C, int ldc, int K,
    const float* __restrict__ bias,
    const float* __restrict__ bn, int bn_ld,
    int accumulate, int relu)
{
    gemm_core(A, lda, gather, B, ldb, C, ldc, K, bias, bn, bn_ld,
              accumulate, relu, blockIdx.x * 64, blockIdx.y * 64);
}

// h-projection: z = class-side (0..4 user-side via W_uc, 5..9 item-side via W_ic)
__global__ __launch_bounds__(256) void gemm_hproj(
    const float* __restrict__ agg,
    const float* __restrict__ W_uc, const float* __restrict__ W_ic,
    float* __restrict__ h_user, float* __restrict__ h_item,
    const float* __restrict__ bn_hu, const float* __restrict__ bn_hi)
{
    int cs = blockIdx.z;
    int c  = cs % NCLASS;
    int side = cs / NCLASS;
    const float* A  = agg + (size_t)cs * NBATCH * DRAW;
    const float* B  = (side == 0 ? W_uc : W_ic) + (size_t)c * DRAW * DCONV;
    float*       C  = (side == 0 ? h_user : h_item) + c * DCONV;
    const float* bn = (side == 0 ? bn_hu : bn_hi) + c * DCONV;
    gemm_core(A, DRAW, nullptr, B, DCONV, C, NCLASS * DCONV, DRAW,
              nullptr, bn, NCLASS * DCONV, 0, 1, blockIdx.x * 64, blockIdx.y * 64);
}

// ============================================================================
// Graph aggregation: CSR build (hist -> scan -> scatter), then row-parallel SpMM
// class-sides: cs 0..4 = user-side (agg item_feat via user_edge_*),
//              cs 5..9 = item-side (agg user_feat via item_edge_*).
// ============================================================================
__global__ __launch_bounds__(256) void hist_kernel(
    const int* __restrict__ u_dst, const int* __restrict__ i_dst,
    int* __restrict__ counts)
{
    const int total = 10 * NEDGE;
    for (int idx = blockIdx.x * 256 + threadIdx.x; idx < total; idx += gridDim.x * 256) {
        int cs = idx / NEDGE;
        int e  = idx - cs * NEDGE;
        int dst = (cs < NCLASS) ? u_dst[cs * NEDGE + e] : i_dst[(cs - NCLASS) * NEDGE + e];
        atomicAdd(&counts[cs * NBATCH + dst], 1);
    }
}

// one block per class-side: exclusive scan of 8192 counts
__global__ __launch_bounds__(256) void scan_kernel(
    const int* __restrict__ counts, int* __restrict__ offsets, int* __restrict__ cursor)
{
    __shared__ int sums[256];
    int cs = blockIdx.x;
    int t  = threadIdx.x;
    int base = cs * NBATCH + t * 32;
    int local[32];
    int s = 0;
    #pragma unroll
    for (int i = 0; i < 32; ++i) { local[i] = s; s += counts[base + i]; }
    sums[t] = s;
    __syncthreads();
    for (int ofs = 1; ofs < 256; ofs <<= 1) {
        int v = (t >= ofs) ? sums[t - ofs] : 0;
        __syncthreads();
        sums[t] += v;
        __syncthreads();
    }
    int excl = (t == 0) ? 0 : sums[t - 1];
    #pragma unroll
    for (int i = 0; i < 32; ++i) {
        int o = excl + local[i];
        offsets[base + i] = o;
        cursor[base + i]  = o;
    }
}

__global__ __launch_bounds__(256) void scatter_kernel(
    const int* __restrict__ u_src, const int* __restrict__ u_dst, const float* __restrict__ u_w,
    const int* __restrict__ i_src, const int* __restrict__ i_dst, const float* __restrict__ i_w,
    int* __restrict__ cursor, int* __restrict__ sorted_src, float* __restrict__ sorted_w)
{
    const int total = 10 * NEDGE;
    for (int idx = blockIdx.x * 256 + threadIdx.x; idx < total; idx += gridDim.x * 256) {
        int cs = idx / NEDGE;
        int e  = idx - cs * NEDGE;
        int src, dst; float w;
        if (cs < NCLASS) {
            int b = cs * NEDGE + e;
            src = u_src[b]; dst = u_dst[b]; w = u_w[b];
        } else {
            int b = (cs - NCLASS) * NEDGE + e;
            src = i_src[b]; dst = i_dst[b]; w = i_w[b];
        }
        int pos = atomicAdd(&cursor[cs * NBATCH + dst], 1);
        sorted_src[(size_t)cs * NEDGE + pos] = src;
        sorted_w  [(size_t)cs * NEDGE + pos] = w;
    }
}

// one wave per (class-side, batch row); lane holds 4 consecutive cols (float4)
__global__ __launch_bounds__(256) void spmm_kernel(
    const float* __restrict__ item_feat, const float* __restrict__ user_feat,
    const int* __restrict__ sorted_src, const float* __restrict__ sorted_w,
    const int* __restrict__ offsets, const int* __restrict__ counts,
    float* __restrict__ agg)
{
    int wave = threadIdx.x >> 6;
    int lane = threadIdx.x & 63;
    int r  = blockIdx.x * 4 + wave;     // 0..8191
    int cs = blockIdx.y;                // 0..9
    const float* feat = (cs < NCLASS) ? item_feat : user_feat;
    int off = offsets[cs * NBATCH + r];
    int cnt = counts [cs * NBATCH + r];
    const int*   ss = sorted_src + (size_t)cs * NEDGE;
    const float* sw = sorted_w   + (size_t)cs * NEDGE;

    float4 acc = make_float4(0.f, 0.f, 0.f, 0.f);
    int e = 0;
    for (; e + 1 < cnt; e += 2) {
        int   s0 = ss[off + e],     s1 = ss[off + e + 1];
        float w0 = sw[off + e],     w1 = sw[off + e + 1];
        float4 v0 = *(const float4*)&feat[(size_t)s0 * DFEAT + lane * 4];
        float4 v1 = *(const float4*)&feat[(size_t)s1 * DFEAT + lane * 4];
        acc.x += w0 * v0.x + w1 * v1.x;
        acc.y += w0 * v0.y + w1 * v1.y;
        acc.z += w0 * v0.z + w1 * v1.z;
        acc.w += w0 * v0.w + w1 * v1.w;
    }
    if (e < cnt) {
        int   s0 = ss[off + e];
        float w0 = sw[off + e];
        float4 v0 = *(const float4*)&feat[(size_t)s0 * DFEAT + lane * 4];
        acc.x += w0 * v0.x;
        acc.y += w0 * v0.y;
        acc.z += w0 * v0.z;
        acc.w += w0 * v0.w;
    }
    *(float4*)&agg[((size_t)cs * NBATCH + r) * DFEAT + lane * 4] = acc;
}

// ============================================================================
// Bilinear decoder final stage: s_k[b] = (u_b @ Wdec[k]) . v_b precomputed as
// t0/t1; here reduce dots + combine with Wcomb -> logits [B,5]
// ============================================================================
__global__ __launch_bounds__(256) void decoder_kernel(
    const float* __restrict__ t0, const float* __restrict__ t1,
    const float* __restrict__ item_emb, const float* __restrict__ Wcomb,
    float* __restrict__ out)
{
    int wave = threadIdx.x >> 6;
    int lane = threadIdx.x & 63;
    int b = blockIdx.x * 4 + wave;   // 0..8191
    const float* ie = item_emb + (size_t)b * DEMB;
    const float* p0 = t0 + (size_t)b * DEMB;
    const float* p1 = t1 + (size_t)b * DEMB;
    float s0 = 0.f, s1 = 0.f;
    #pragma unroll
    for (int j = lane; j < DEMB; j += 64) {
        float v = ie[j];
        s0 += p0[j] * v;
        s1 += p1[j] * v;
    }
    #pragma unroll
    for (int o = 32; o > 0; o >>= 1) {
        s0 += __shfl_down(s0, o);
        s1 += __shfl_down(s1, o);
    }
    if (lane == 0) {
        #pragma unroll
        for (int r = 0; r < NCLASS; ++r)
            out[b * NCLASS + r] = Wcomb[r * 2 + 0] * s0 + Wcomb[r * 2 + 1] * s1;
    }
}

// ============================================================================
// launch
// ============================================================================
extern "C" void kernel_launch(void* const* d_in, const int* in_sizes, int n_in,
                              void* d_out, int out_size, void* d_ws, size_t ws_size,
                              hipStream_t stream)
{
    const float* user_feat = (const float*)d_in[0];
    const float* item_feat = (const float*)d_in[1];
    const int*   user_idx  = (const int*)  d_in[2];
    const int*   item_idx  = (const int*)  d_in[3];
    const int*   u_src     = (const int*)  d_in[4];
    const int*   u_dst     = (const int*)  d_in[5];
    const float* u_w       = (const float*)d_in[6];
    const int*   i_src     = (const int*)  d_in[7];
    const int*   i_dst     = (const int*)  d_in[8];
    const float* i_w       = (const float*)d_in[9];
    const float* W_fu      = (const float*)d_in[10];
    const float* b_fu      = (const float*)d_in[11];
    const float* W_fi      = (const float*)d_in[12];
    const float* b_fi      = (const float*)d_in[13];
    const float* W_uc      = (const float*)d_in[14];
    const float* W_ic      = (const float*)d_in[15];
    const float* bn_fu     = (const float*)d_in[16];
    const float* bn_hu     = (const float*)d_in[17];
    const float* bn_fi     = (const float*)d_in[18];
    const float* bn_hi     = (const float*)d_in[19];
    const float* W2_fu     = (const float*)d_in[20];
    const float* W2_hu     = (const float*)d_in[21];
    const float* W2_fi     = (const float*)d_in[22];
    const float* W2_hi     = (const float*)d_in[23];
    const float* Wdec      = (const float*)d_in[24];
    const float* Wcomb     = (const float*)d_in[25];
    float* out = (float*)d_out;

    // ---- workspace layout (all 256B-aligned) -------------------------------
    char* ws = (char*)d_ws;
    int*   counts     = (int*)  (ws + 0);            //  10*8192 i32   = 320 KB
    int*   offsets    = (int*)  (ws + 327680);       //  10*8192 i32
    int*   cursor     = (int*)  (ws + 655360);       //  10*8192 i32
    int*   sorted_src = (int*)  (ws + 983040);       //  10*E i32      = 20 MB
    float* sorted_w   = (float*)(ws + 20983040);     //  10*E f32      = 20 MB
    float* agg        = (float*)(ws + 40983040);     //  10*8192*256   = 80 MB
    float* f_user     = (float*)(ws + 124869120);    //  8192*256      = 8 MB
    float* f_item     = (float*)(ws + 133257728);
    float* h_user     = (float*)(ws + 141646336);    //  8192*640      = 21 MB
    float* h_item     = (float*)(ws + 162617856);
    float* user_emb   = (float*)(ws + 183589376);    //  8192*256
    float* item_emb   = (float*)(ws + 191977984);    //  total 200,366,592 B

    // ---- 1. CSR build ------------------------------------------------------
    hipMemsetAsync(counts, 0, 10 * NBATCH * sizeof(int), stream);
    hist_kernel<<<2048, 256, 0, stream>>>(u_dst, i_dst, counts);
    scan_kernel<<<10, 256, 0, stream>>>(counts, offsets, cursor);
    scatter_kernel<<<2048, 256, 0, stream>>>(u_src, u_dst, u_w, i_src, i_dst, i_w,
                                             cursor, sorted_src, sorted_w);

    // ---- 2. SpMM aggregation (10 class-sides) ------------------------------
    spmm_kernel<<<dim3(NBATCH / 4, 10), 256, 0, stream>>>(
        item_feat, user_feat, sorted_src, sorted_w, offsets, counts, agg);

    // ---- 3. f path: relu(bn(gather @ W + b)) -------------------------------
    dim3 g256(NBATCH / 64, DRAW / 64);   // (128,4)
    gemm_plain<<<g256, 256, 0, stream>>>(user_feat, DFEAT, user_idx, W_fu, DRAW,
                                         f_user, DRAW, DFEAT, b_fu, bn_fu, DRAW, 0, 1);
    gemm_plain<<<g256, 256, 0, stream>>>(item_feat, DFEAT, item_idx, W_fi, DRAW,
                                         f_item, DRAW, DFEAT, b_fi, bn_fi, DRAW, 0, 1);

    // ---- 4. h path: relu(bn(agg @ Wc)) per class-side ----------------------
    gemm_hproj<<<dim3(NBATCH / 64, DCONV / 64, 10), 256, 0, stream>>>(
        agg, W_uc, W_ic, h_user, h_item, bn_hu, bn_hi);

    // ---- 5. embeddings: relu(f @ W2_f + h @ W2_h) --------------------------
    gemm_plain<<<g256, 256, 0, stream>>>(f_user, DRAW, nullptr, W2_fu, DEMB,
                                         user_emb, DEMB, DRAW, nullptr, nullptr, 0, 0, 0);
    gemm_plain<<<g256, 256, 0, stream>>>(h_user, NCLASS * DCONV, nullptr, W2_hu, DEMB,
                                         user_emb, DEMB, NCLASS * DCONV, nullptr, nullptr, 0, 1, 1);
    gemm_plain<<<g256, 256, 0, stream>>>(f_item, DRAW, nullptr, W2_fi, DEMB,
                                         item_emb, DEMB, DRAW, nullptr, nullptr, 0, 0, 0);
    gemm_plain<<<g256, 256, 0, stream>>>(h_item, NCLASS * DCONV, nullptr, W2_hi, DEMB,
                                         item_emb, DEMB, NCLASS * DCONV, nullptr, nullptr, 0, 1, 1);

    // ---- 6. decoder: t_k = user_emb @ Wdec[k]; logits ----------------------
    float* t0 = f_user;   // f_* are dead now -> reuse
    float* t1 = f_item;
    gemm_plain<<<g256, 256, 0, stream>>>(user_emb, DEMB, nullptr, Wdec, DEMB,
                                         t0, DEMB, DEMB, nullptr, nullptr, 0, 0, 0);
    gemm_plain<<<g256, 256, 0, stream>>>(user_emb, DEMB, nullptr, Wdec + DEMB * DEMB, DEMB,
                                         t1, DEMB, DEMB, nullptr, nullptr, 0, 0, 0);
    decoder_kernel<<<NBATCH / 4, 256, 0, stream>>>(t0, t1, item_emb, Wcomb, out);
}

// Round 2
// 1221.383 us; speedup vs baseline: 1.4607x; 1.4607x over previous
//
#include <hip/hip_runtime.h>
#include <cstdint>
#include <cstddef>

// Problem constants
#define NBATCH   8192
#define DFEAT    256
#define DCONV    128
#define NCLASS   5
#define NEDGE    500000
#define NUSERS   100000
#define BN_EPS   1e-3f

typedef unsigned short u16;
typedef short bf16x8_t __attribute__((ext_vector_type(8)));
typedef float f32x4_t  __attribute__((ext_vector_type(4)));

__device__ __forceinline__ u16 f2bf(float x) {
    unsigned u = __float_as_uint(x);
    u += 0x7FFF + ((u >> 16) & 1);
    return (u16)(u >> 16);
}
__device__ __forceinline__ float bf2f(u16 h) {
    return __uint_as_float(((unsigned)h) << 16);
}

// ============================================================================
// bf16 MFMA GEMM core: tile 64x64, block = 256 threads (4 waves), K-step 32.
// A row-major [M x K] bf16 (optionally row-gathered); BT row-major [N x K] bf16.
// LDS is fragment-ordered: slot (band*64 + lane)*8 holds the 8 contiguous-k
// bf16 the mfma lane needs -> all ds traffic is conflict-free b128.
//   A-frag: lane l holds A[m = l&15][k = (l>>4)*8 + j]
//   B-frag: lane l holds BT[n = l&15][k = (l>>4)*8 + j]
//   C/D:    lane l, reg r -> row = (l>>4)*4 + r, col = l&15   (m89-verified)
// ============================================================================
__device__ __forceinline__ void mfma_tiles(
    const u16* __restrict__ A, int lda, const int* __restrict__ gather,
    const u16* __restrict__ BT, int K,
    int tileM, int tileN, u16* As, u16* Bs, f32x4_t acc[4])
{
    const int t    = threadIdx.x;
    const int rowi = t >> 2;      // 0..63
    const int kc   = t & 3;       // 16B chunk within 32-k step
    const int w    = t >> 6;
    const int lane = t & 63;

    int ar = gather ? gather[tileM + rowi] : (tileM + rowi);
    const u16* Ap = A  + (size_t)ar * lda + kc * 8;
    const u16* Bp = BT + (size_t)(tileN + rowi) * K + kc * 8;
    u16* Aw = As + (size_t)(((rowi >> 4) * 64) + (rowi & 15) + 16 * kc) * 8;
    u16* Bw = Bs + (size_t)(((rowi >> 4) * 64) + (rowi & 15) + 16 * kc) * 8;
    const u16* Ar = As + (size_t)(w * 64 + lane) * 8;

    for (int k0 = 0; k0 < K; k0 += 32) {
        __syncthreads();                       // LDS reuse hazard from prev step
        *(uint4*)Aw = *(const uint4*)(Ap + k0);
        *(uint4*)Bw = *(const uint4*)(Bp + k0);
        __syncthreads();
        bf16x8_t av = *(const bf16x8_t*)Ar;
        #pragma unroll
        for (int nb = 0; nb < 4; ++nb) {
            bf16x8_t bv = *(const bf16x8_t*)(Bs + (size_t)(nb * 64 + lane) * 8);
            acc[nb] = __builtin_amdgcn_mfma_f32_16x16x32_bf16(av, bv, acc[nb], 0, 0, 0);
        }
    }
}

// epilogue: optional bias[n], BN (packed 4 x bn_ld), relu; store bf16 or f32
__device__ __forceinline__ void epilogue(
    f32x4_t acc[4], int tileM, int tileN,
    const float* __restrict__ bias, const float* __restrict__ bn, int bn_ld,
    int relu, u16* __restrict__ out_bf, float* __restrict__ out_f32, int ldc)
{
    const int t = threadIdx.x, w = t >> 6, lane = t & 63;
    const int row0 = tileM + w * 16 + (lane >> 4) * 4;
    #pragma unroll
    for (int nb = 0; nb < 4; ++nb) {
        int col = tileN + nb * 16 + (lane & 15);
        float g = 1.f, be = 0.f, mu = 0.f, va = 1.f, bs = 0.f;
        if (bn)   { g = bn[col]; be = bn[bn_ld + col]; mu = bn[2 * bn_ld + col]; va = bn[3 * bn_ld + col]; }
        if (bias) bs = bias[col];
        #pragma unroll
        for (int r = 0; r < 4; ++r) {
            float x = acc[nb][r] + bs;
            if (bn)   x = g * (x - mu) * rsqrtf(va + BN_EPS) + be;
            if (relu) x = fmaxf(x, 0.f);
            size_t o = (size_t)(row0 + r) * ldc + col;
            if (out_bf) out_bf[o] = f2bf(x);
            else        out_f32[o] = x;
        }
    }
}

// f path: relu(bn(gathered_feat @ W + b)) -> bf16 [8192 x 256]
__global__ __launch_bounds__(256) void k_gemm_f(
    const u16* __restrict__ feat_bf, const int* __restrict__ idx,
    const u16* __restrict__ WT, const float* __restrict__ bias,
    const float* __restrict__ bn, u16* __restrict__ out)
{
    __shared__ __align__(16) u16 As[2048], Bs[2048];
    f32x4_t z = {0.f, 0.f, 0.f, 0.f};
    f32x4_t acc[4] = {z, z, z, z};
    int tileM = blockIdx.x * 64, tileN = blockIdx.y * 64;
    mfma_tiles(feat_bf, 256, idx, WT, 256, tileM, tileN, As, Bs, acc);
    epilogue(acc, tileM, tileN, bias, bn, 256, 1, out, nullptr, 256);
}

// h projection: relu(bn(agg_cs @ Wc)) per class-side -> bf16 [8192 x 640]
__global__ __launch_bounds__(256) void k_hproj(
    const u16* __restrict__ agg, const u16* __restrict__ WucT, const u16* __restrict__ WicT,
    const float* __restrict__ bn_hu, const float* __restrict__ bn_hi,
    u16* __restrict__ h_user, u16* __restrict__ h_item)
{
    __shared__ __align__(16) u16 As[2048], Bs[2048];
    f32x4_t z = {0.f, 0.f, 0.f, 0.f};
    f32x4_t acc[4] = {z, z, z, z};
    int cs = blockIdx.z, c = cs % NCLASS, side = cs / NCLASS;
    const u16* A  = agg + (size_t)cs * NBATCH * DFEAT;
    const u16* BT = (side ? WicT : WucT) + (size_t)c * DCONV * DFEAT;
    const float* bn = (side ? bn_hi : bn_hu) + c * DCONV;
    u16* out = (side ? h_item : h_user) + c * DCONV;
    int tileM = blockIdx.x * 64, tileN = blockIdx.y * 64;
    mfma_tiles(A, 256, nullptr, BT, 256, tileM, tileN, As, Bs, acc);
    epilogue(acc, tileM, tileN, nullptr, bn, NCLASS * DCONV, 1, out, nullptr, NCLASS * DCONV);
}

// embedding: relu(f @ W2f + h @ W2h) -> bf16 [8192 x 256] (fused K = 256 + 640)
__global__ __launch_bounds__(256) void k_emb(
    const u16* __restrict__ fbf, const u16* __restrict__ hbf,
    const u16* __restrict__ W2fT, const u16* __restrict__ W2hT,
    u16* __restrict__ emb)
{
    __shared__ __align__(16) u16 As[2048], Bs[2048];
    f32x4_t z = {0.f, 0.f, 0.f, 0.f};
    f32x4_t acc[4] = {z, z, z, z};
    int tileM = blockIdx.x * 64, tileN = blockIdx.y * 64;
    mfma_tiles(fbf, 256, nullptr, W2fT, 256, tileM, tileN, As, Bs, acc);
    mfma_tiles(hbf, NCLASS * DCONV, nullptr, W2hT, NCLASS * DCONV, tileM, tileN, As, Bs, acc);
    epilogue(acc, tileM, tileN, nullptr, nullptr, 0, 1, emb, nullptr, 256);
}

// decoder stage 1: t_z = user_emb @ Wdec[z] -> f32 [8192 x 256]
__global__ __launch_bounds__(256) void k_dec(
    const u16* __restrict__ emb, const u16* __restrict__ WdecT,
    float* __restrict__ t0, float* __restrict__ t1)
{
    __shared__ __align__(16) u16 As[2048], Bs[2048];
    f32x4_t z = {0.f, 0.f, 0.f, 0.f};
    f32x4_t acc[4] = {z, z, z, z};
    int zi = blockIdx.z;
    const u16* BT = WdecT + (size_t)zi * 256 * 256;
    float* out = zi ? t1 : t0;
    int tileM = blockIdx.x * 64, tileN = blockIdx.y * 64;
    mfma_tiles(emb, 256, nullptr, BT, 256, tileM, tileN, As, Bs, acc);
    epilogue(acc, tileM, tileN, nullptr, nullptr, 0, 0, nullptr, out, 256);
}

// ============================================================================
// prep: fp32 -> bf16 feature conversion; weight convert+transpose to [N][K]
// ============================================================================
__global__ __launch_bounds__(256) void cvt_feat(
    const float* __restrict__ uf, const float* __restrict__ itf,
    u16* __restrict__ ubf, u16* __restrict__ ibf)
{
    const size_t n4 = (size_t)NUSERS * DFEAT / 4;   // float4 chunks per table
    for (size_t i = (size_t)blockIdx.x * 256 + threadIdx.x; i < 2 * n4;
         i += (size_t)gridDim.x * 256) {
        bool u = i < n4;
        size_t j = u ? i : i - n4;
        float4 v = u ? ((const float4*)uf)[j] : ((const float4*)itf)[j];
        ushort4 o;
        o.x = f2bf(v.x); o.y = f2bf(v.y); o.z = f2bf(v.z); o.w = f2bf(v.w);
        ((ushort4*)(u ? ubf : ibf))[j] = o;
    }
}

// weight-T element offsets within wT arena (elements)
#define OFF_WFU   0
#define OFF_WFI   65536
#define OFF_WUC   131072
#define OFF_WIC   294912
#define OFF_W2FU  458752
#define OFF_W2HU  524288
#define OFF_W2FI  688128
#define OFF_W2HI  753664
#define OFF_WDEC  917504

__global__ __launch_bounds__(256) void cvt_wt(
    const float* __restrict__ Wfu, const float* __restrict__ Wfi,
    const float* __restrict__ Wuc, const float* __restrict__ Wic,
    const float* __restrict__ W2fu, const float* __restrict__ W2hu,
    const float* __restrict__ W2fi, const float* __restrict__ W2hi,
    const float* __restrict__ Wdec, u16* __restrict__ wT)
{
    const float* in; u16* out; int K, N, B;
    switch (blockIdx.y) {
        case 0: in = Wfu;  out = wT + OFF_WFU;  K = 256; N = 256; B = 1; break;
        case 1: in = Wfi;  out = wT + OFF_WFI;  K = 256; N = 256; B = 1; break;
        case 2: in = Wuc;  out = wT + OFF_WUC;  K = 256; N = 128; B = 5; break;
        case 3: in = Wic;  out = wT + OFF_WIC;  K = 256; N = 128; B = 5; break;
        case 4: in = W2fu; out = wT + OFF_W2FU; K = 256; N = 256; B = 1; break;
        case 5: in = W2hu; out = wT + OFF_W2HU; K = 640; N = 256; B = 1; break;
        case 6: in = W2fi; out = wT + OFF_W2FI; K = 256; N = 256; B = 1; break;
        case 7: in = W2hi; out = wT + OFF_W2HI; K = 640; N = 256; B = 1; break;
        default: in = Wdec; out = wT + OFF_WDEC; K = 256; N = 256; B = 2; break;
    }
    int total = B * K * N;
    for (int idx = blockIdx.x * 256 + threadIdx.x; idx < total; idx += gridDim.x * 256) {
        int b = idx / (K * N);
        int r = idx - b * K * N;
        int n = r / K;
        int k = r - n * K;
        out[idx] = f2bf(in[(size_t)(b * K + k) * N + n]);   // out[b][n][k] = in[b][k][n]
    }
}

// ============================================================================
// CSR build + SpMM (bf16 features, fp32 accumulate, bf16 agg out)
// ============================================================================
__global__ __launch_bounds__(256) void hist_kernel(
    const int* __restrict__ u_dst, const int* __restrict__ i_dst, int* __restrict__ counts)
{
    const int total = 10 * NEDGE;
    for (int idx = blockIdx.x * 256 + threadIdx.x; idx < total; idx += gridDim.x * 256) {
        int cs = idx / NEDGE;
        int e  = idx - cs * NEDGE;
        int dst = (cs < NCLASS) ? u_dst[cs * NEDGE + e] : i_dst[(cs - NCLASS) * NEDGE + e];
        atomicAdd(&counts[cs * NBATCH + dst], 1);
    }
}

__global__ __launch_bounds__(256) void scan_kernel(
    const int* __restrict__ counts, int* __restrict__ offsets, int* __restrict__ cursor)
{
    __shared__ int sums[256];
    int cs = blockIdx.x, t = threadIdx.x;
    int base = cs * NBATCH + t * 32;
    int local[32];
    int s = 0;
    #pragma unroll
    for (int i = 0; i < 32; ++i) { local[i] = s; s += counts[base + i]; }
    sums[t] = s;
    __syncthreads();
    for (int ofs = 1; ofs < 256; ofs <<= 1) {
        int v = (t >= ofs) ? sums[t - ofs] : 0;
        __syncthreads();
        sums[t] += v;
        __syncthreads();
    }
    int excl = (t == 0) ? 0 : sums[t - 1];
    #pragma unroll
    for (int i = 0; i < 32; ++i) {
        int o = excl + local[i];
        offsets[base + i] = o;
        cursor[base + i]  = o;
    }
}

__global__ __launch_bounds__(256) void scatter_kernel(
    const int* __restrict__ u_src, const int* __restrict__ u_dst, const float* __restrict__ u_w,
    const int* __restrict__ i_src, const int* __restrict__ i_dst, const float* __restrict__ i_w,
    int* __restrict__ cursor, int* __restrict__ sorted_src, float* __restrict__ sorted_w)
{
    const int total = 10 * NEDGE;
    for (int idx = blockIdx.x * 256 + threadIdx.x; idx < total; idx += gridDim.x * 256) {
        int cs = idx / NEDGE;
        int e  = idx - cs * NEDGE;
        int src, dst; float w;
        if (cs < NCLASS) {
            int b = cs * NEDGE + e;
            src = u_src[b]; dst = u_dst[b]; w = u_w[b];
        } else {
            int b = (cs - NCLASS) * NEDGE + e;
            src = i_src[b]; dst = i_dst[b]; w = i_w[b];
        }
        int pos = atomicAdd(&cursor[cs * NBATCH + dst], 1);
        sorted_src[(size_t)cs * NEDGE + pos] = src;
        sorted_w  [(size_t)cs * NEDGE + pos] = w;
    }
}

// one wave per (class-side, row); lane covers 4 cols; bf16 rows (512 B/edge)
__global__ __launch_bounds__(256) void spmm_kernel(
    const u16* __restrict__ item_bf, const u16* __restrict__ user_bf,
    const int* __restrict__ sorted_src, const float* __restrict__ sorted_w,
    const int* __restrict__ offsets, const int* __restrict__ counts,
    u16* __restrict__ agg)
{
    int wave = threadIdx.x >> 6;
    int lane = threadIdx.x & 63;
    int r  = blockIdx.x * 4 + wave;
    int cs = blockIdx.y;
    const u16* feat = (cs < NCLASS) ? item_bf : user_bf;
    int off = offsets[cs * NBATCH + r];
    int cnt = counts [cs * NBATCH + r];
    const int*   ss = sorted_src + (size_t)cs * NEDGE;
    const float* sw = sorted_w   + (size_t)cs * NEDGE;

    float4 acc = make_float4(0.f, 0.f, 0.f, 0.f);
    int e = 0;
    for (; e + 3 < cnt; e += 4) {
        int   s0 = ss[off + e], s1 = ss[off + e + 1], s2 = ss[off + e + 2], s3 = ss[off + e + 3];
        float w0 = sw[off + e], w1 = sw[off + e + 1], w2 = sw[off + e + 2], w3 = sw[off + e + 3];
        ushort4 v0 = *(const ushort4*)&feat[(size_t)s0 * DFEAT + lane * 4];
        ushort4 v1 = *(const ushort4*)&feat[(size_t)s1 * DFEAT + lane * 4];
        ushort4 v2 = *(const ushort4*)&feat[(size_t)s2 * DFEAT + lane * 4];
        ushort4 v3 = *(const ushort4*)&feat[(size_t)s3 * DFEAT + lane * 4];
        acc.x += w0 * bf2f(v0.x) + w1 * bf2f(v1.x) + w2 * bf2f(v2.x) + w3 * bf2f(v3.x);
        acc.y += w0 * bf2f(v0.y) + w1 * bf2f(v1.y) + w2 * bf2f(v2.y) + w3 * bf2f(v3.y);
        acc.z += w0 * bf2f(v0.z) + w1 * bf2f(v1.z) + w2 * bf2f(v2.z) + w3 * bf2f(v3.z);
        acc.w += w0 * bf2f(v0.w) + w1 * bf2f(v1.w) + w2 * bf2f(v2.w) + w3 * bf2f(v3.w);
    }
    for (; e < cnt; ++e) {
        int   s0 = ss[off + e];
        float w0 = sw[off + e];
        ushort4 v0 = *(const ushort4*)&feat[(size_t)s0 * DFEAT + lane * 4];
        acc.x += w0 * bf2f(v0.x);
        acc.y += w0 * bf2f(v0.y);
        acc.z += w0 * bf2f(v0.z);
        acc.w += w0 * bf2f(v0.w);
    }
    ushort4 o;
    o.x = f2bf(acc.x); o.y = f2bf(acc.y); o.z = f2bf(acc.z); o.w = f2bf(acc.w);
    *(ushort4*)&agg[((size_t)cs * NBATCH + r) * DFEAT + lane * 4] = o;
}

// decoder stage 2: logits[b,r] = sum_k Wcomb[r,k] * (t_k[b,:] . item_emb[b,:])
__global__ __launch_bounds__(256) void decoder_kernel(
    const float* __restrict__ t0, const float* __restrict__ t1,
    const u16* __restrict__ item_emb, const float* __restrict__ Wcomb,
    float* __restrict__ out)
{
    int wave = threadIdx.x >> 6;
    int lane = threadIdx.x & 63;
    int b = blockIdx.x * 4 + wave;
    const u16*   ie = item_emb + (size_t)b * 256;
    const float* p0 = t0 + (size_t)b * 256;
    const float* p1 = t1 + (size_t)b * 256;
    float s0 = 0.f, s1 = 0.f;
    #pragma unroll
    for (int j = lane; j < 256; j += 64) {
        float v = bf2f(ie[j]);
        s0 += p0[j] * v;
        s1 += p1[j] * v;
    }
    #pragma unroll
    for (int o = 32; o > 0; o >>= 1) {
        s0 += __shfl_down(s0, o);
        s1 += __shfl_down(s1, o);
    }
    if (lane == 0) {
        #pragma unroll
        for (int r = 0; r < NCLASS; ++r)
            out[b * NCLASS + r] = Wcomb[r * 2 + 0] * s0 + Wcomb[r * 2 + 1] * s1;
    }
}

// ============================================================================
// launch
// ============================================================================
extern "C" void kernel_launch(void* const* d_in, const int* in_sizes, int n_in,
                              void* d_out, int out_size, void* d_ws, size_t ws_size,
                              hipStream_t stream)
{
    const float* user_feat = (const float*)d_in[0];
    const float* item_feat = (const float*)d_in[1];
    const int*   user_idx  = (const int*)  d_in[2];
    const int*   item_idx  = (const int*)  d_in[3];
    const int*   u_src     = (const int*)  d_in[4];
    const int*   u_dst     = (const int*)  d_in[5];
    const float* u_w       = (const float*)d_in[6];
    const int*   i_src     = (const int*)  d_in[7];
    const int*   i_dst     = (const int*)  d_in[8];
    const float* i_w       = (const float*)d_in[9];
    const float* W_fu      = (const float*)d_in[10];
    const float* b_fu      = (const float*)d_in[11];
    const float* W_fi      = (const float*)d_in[12];
    const float* b_fi      = (const float*)d_in[13];
    const float* W_uc      = (const float*)d_in[14];
    const float* W_ic      = (const float*)d_in[15];
    const float* bn_fu     = (const float*)d_in[16];
    const float* bn_hu     = (const float*)d_in[17];
    const float* bn_fi     = (const float*)d_in[18];
    const float* bn_hi     = (const float*)d_in[19];
    const float* W2_fu     = (const float*)d_in[20];
    const float* W2_hu     = (const float*)d_in[21];
    const float* W2_fi     = (const float*)d_in[22];
    const float* W2_hi     = (const float*)d_in[23];
    const float* Wdec      = (const float*)d_in[24];
    const float* Wcomb     = (const float*)d_in[25];
    float* out = (float*)d_out;

    // ---- workspace layout (187.4 MB total; R1 proved ws_size >= 200.4 MB) --
    char* ws = (char*)d_ws;
    int*   counts     = (int*)  (ws + 0);            // 10*8192 i32
    int*   offsets    = (int*)  (ws + 327680);
    int*   cursor     = (int*)  (ws + 655360);
    int*   sorted_src = (int*)  (ws + 983040);       // 20 MB  (dead after spmm)
    float* sorted_w   = (float*)(ws + 20983040);     // 20 MB  (dead after spmm)
    u16*   user_bf    = (u16*)  (ws + 40983040);     // 51.2 MB
    u16*   item_bf    = (u16*)  (ws + 92183040);     // 51.2 MB
    u16*   agg_bf     = (u16*)  (ws + 143383040);    // 41.9 MB (dead after hproj)
    u16*   wT         = (u16*)  (ws + 185326080);    // 2.1 MB weightsT arena
    // overlays on sorted region (live f-gemm..emb, after spmm):
    u16*   f_user_bf  = (u16*)  (ws + 983040);       // 4.2 MB
    u16*   f_item_bf  = (u16*)  (ws + 5177344);      // 4.2 MB
    u16*   h_user_bf  = (u16*)  (ws + 9371648);      // 10.5 MB
    u16*   h_item_bf  = (u16*)  (ws + 19857408);     // 10.5 MB
    // overlays on agg region (live emb..decoder, after hproj):
    float* t0         = (float*)(ws + 143383040);    // 8.4 MB
    float* t1         = (float*)(ws + 151771648);    // 8.4 MB
    u16*   user_emb   = (u16*)  (ws + 160160256);    // 4.2 MB
    u16*   item_emb   = (u16*)  (ws + 164354560);    // 4.2 MB

    // ---- 1. CSR build ------------------------------------------------------
    hipMemsetAsync(counts, 0, 10 * NBATCH * sizeof(int), stream);
    hist_kernel<<<2048, 256, 0, stream>>>(u_dst, i_dst, counts);
    scan_kernel<<<10, 256, 0, stream>>>(counts, offsets, cursor);
    scatter_kernel<<<2048, 256, 0, stream>>>(u_src, u_dst, u_w, i_src, i_dst, i_w,
                                             cursor, sorted_src, sorted_w);

    // ---- 2. prep conversions ----------------------------------------------
    cvt_feat<<<4096, 256, 0, stream>>>(user_feat, item_feat, user_bf, item_bf);
    cvt_wt<<<dim3(160, 9), 256, 0, stream>>>(W_fu, W_fi, W_uc, W_ic,
                                             W2_fu, W2_hu, W2_fi, W2_hi, Wdec, wT);

    // ---- 3. SpMM aggregation (must precede f/h overlays on sorted region) --
    spmm_kernel<<<dim3(NBATCH / 4, 10), 256, 0, stream>>>(
        item_bf, user_bf, sorted_src, sorted_w, offsets, counts, agg_bf);

    // ---- 4. f path ---------------------------------------------------------
    k_gemm_f<<<dim3(128, 4), 256, 0, stream>>>(user_bf, user_idx, wT + OFF_WFU,
                                               b_fu, bn_fu, f_user_bf);
    k_gemm_f<<<dim3(128, 4), 256, 0, stream>>>(item_bf, item_idx, wT + OFF_WFI,
                                               b_fi, bn_fi, f_item_bf);

    // ---- 5. h projection ---------------------------------------------------
    k_hproj<<<dim3(128, 2, 10), 256, 0, stream>>>(agg_bf, wT + OFF_WUC, wT + OFF_WIC,
                                                  bn_hu, bn_hi, h_user_bf, h_item_bf);

    // ---- 6. embeddings (agg dead -> emb/t overlays become writable) --------
    k_emb<<<dim3(128, 4), 256, 0, stream>>>(f_user_bf, h_user_bf,
                                            wT + OFF_W2FU, wT + OFF_W2HU, user_emb);
    k_emb<<<dim3(128, 4), 256, 0, stream>>>(f_item_bf, h_item_bf,
                                            wT + OFF_W2FI, wT + OFF_W2HI, item_emb);

    // ---- 7. decoder --------------------------------------------------------
    k_dec<<<dim3(128, 4, 2), 256, 0, stream>>>(user_emb, wT + OFF_WDEC, t0, t1);
    decoder_kernel<<<NBATCH / 4, 256, 0, stream>>>(t0, t1, item_emb, Wcomb, out);
}

// Round 3
// 1140.968 us; speedup vs baseline: 1.5636x; 1.0705x over previous
//
#include <hip/hip_runtime.h>
#include <cstdint>
#include <cstddef>

// Problem constants
#define NBATCH   8192
#define DFEAT    256
#define DCONV    128
#define NCLASS   5
#define NEDGE    500000
#define NUSERS   100000
#define BN_EPS   1e-3f
#define NPASS    4      // scatter dst-range passes (write-locality)

typedef unsigned short u16;
typedef short bf16x8_t __attribute__((ext_vector_type(8)));
typedef float f32x4_t  __attribute__((ext_vector_type(4)));

__device__ __forceinline__ u16 f2bf(float x) {
    unsigned u = __float_as_uint(x);
    u += 0x7FFF + ((u >> 16) & 1);
    return (u16)(u >> 16);
}
__device__ __forceinline__ float bf2f(u16 h) {
    return __uint_as_float(((unsigned)h) << 16);
}

// ============================================================================
// bf16 MFMA GEMM core: tile 64x64, block = 256 threads (4 waves), K-step 32.
// A row-major [M x K] bf16 (optionally row-gathered); BT row-major [N x K] bf16.
// LDS fragment-ordered -> all ds traffic conflict-free b128.
//   A-frag: lane l holds A[m = l&15][k = (l>>4)*8 + j]
//   B-frag: lane l holds BT[n = l&15][k = (l>>4)*8 + j]
//   C/D:    lane l, reg r -> row = (l>>4)*4 + r, col = l&15   (m89-verified)
// ============================================================================
__device__ __forceinline__ void mfma_tiles(
    const u16* __restrict__ A, int lda, const int* __restrict__ gather,
    const u16* __restrict__ BT, int K,
    int tileM, int tileN, u16* As, u16* Bs, f32x4_t acc[4])
{
    const int t    = threadIdx.x;
    const int rowi = t >> 2;      // 0..63
    const int kc   = t & 3;       // 16B chunk within 32-k step
    const int w    = t >> 6;
    const int lane = t & 63;

    int ar = gather ? gather[tileM + rowi] : (tileM + rowi);
    const u16* Ap = A  + (size_t)ar * lda + kc * 8;
    const u16* Bp = BT + (size_t)(tileN + rowi) * K + kc * 8;
    u16* Aw = As + (size_t)(((rowi >> 4) * 64) + (rowi & 15) + 16 * kc) * 8;
    u16* Bw = Bs + (size_t)(((rowi >> 4) * 64) + (rowi & 15) + 16 * kc) * 8;
    const u16* Ar = As + (size_t)(w * 64 + lane) * 8;

    for (int k0 = 0; k0 < K; k0 += 32) {
        __syncthreads();                       // LDS reuse hazard from prev step
        *(uint4*)Aw = *(const uint4*)(Ap + k0);
        *(uint4*)Bw = *(const uint4*)(Bp + k0);
        __syncthreads();
        bf16x8_t av = *(const bf16x8_t*)Ar;
        #pragma unroll
        for (int nb = 0; nb < 4; ++nb) {
            bf16x8_t bv = *(const bf16x8_t*)(Bs + (size_t)(nb * 64 + lane) * 8);
            acc[nb] = __builtin_amdgcn_mfma_f32_16x16x32_bf16(av, bv, acc[nb], 0, 0, 0);
        }
    }
}

__device__ __forceinline__ void epilogue(
    f32x4_t acc[4], int tileM, int tileN,
    const float* __restrict__ bias, const float* __restrict__ bn, int bn_ld,
    int relu, u16* __restrict__ out_bf, float* __restrict__ out_f32, int ldc)
{
    const int t = threadIdx.x, w = t >> 6, lane = t & 63;
    const int row0 = tileM + w * 16 + (lane >> 4) * 4;
    #pragma unroll
    for (int nb = 0; nb < 4; ++nb) {
        int col = tileN + nb * 16 + (lane & 15);
        float g = 1.f, be = 0.f, mu = 0.f, va = 1.f, bs = 0.f;
        if (bn)   { g = bn[col]; be = bn[bn_ld + col]; mu = bn[2 * bn_ld + col]; va = bn[3 * bn_ld + col]; }
        if (bias) bs = bias[col];
        #pragma unroll
        for (int r = 0; r < 4; ++r) {
            float x = acc[nb][r] + bs;
            if (bn)   x = g * (x - mu) * rsqrtf(va + BN_EPS) + be;
            if (relu) x = fmaxf(x, 0.f);
            size_t o = (size_t)(row0 + r) * ldc + col;
            if (out_bf) out_bf[o] = f2bf(x);
            else        out_f32[o] = x;
        }
    }
}

__global__ __launch_bounds__(256) void k_gemm_f(
    const u16* __restrict__ feat_bf, const int* __restrict__ idx,
    const u16* __restrict__ WT, const float* __restrict__ bias,
    const float* __restrict__ bn, u16* __restrict__ out)
{
    __shared__ __align__(16) u16 As[2048], Bs[2048];
    f32x4_t z = {0.f, 0.f, 0.f, 0.f};
    f32x4_t acc[4] = {z, z, z, z};
    int tileM = blockIdx.x * 64, tileN = blockIdx.y * 64;
    mfma_tiles(feat_bf, 256, idx, WT, 256, tileM, tileN, As, Bs, acc);
    epilogue(acc, tileM, tileN, bias, bn, 256, 1, out, nullptr, 256);
}

__global__ __launch_bounds__(256) void k_hproj(
    const u16* __restrict__ agg, const u16* __restrict__ WucT, const u16* __restrict__ WicT,
    const float* __restrict__ bn_hu, const float* __restrict__ bn_hi,
    u16* __restrict__ h_user, u16* __restrict__ h_item)
{
    __shared__ __align__(16) u16 As[2048], Bs[2048];
    f32x4_t z = {0.f, 0.f, 0.f, 0.f};
    f32x4_t acc[4] = {z, z, z, z};
    int cs = blockIdx.z, c = cs % NCLASS, side = cs / NCLASS;
    const u16* A  = agg + (size_t)cs * NBATCH * DFEAT;
    const u16* BT = (side ? WicT : WucT) + (size_t)c * DCONV * DFEAT;
    const float* bn = (side ? bn_hi : bn_hu) + c * DCONV;
    u16* out = (side ? h_item : h_user) + c * DCONV;
    int tileM = blockIdx.x * 64, tileN = blockIdx.y * 64;
    mfma_tiles(A, 256, nullptr, BT, 256, tileM, tileN, As, Bs, acc);
    epilogue(acc, tileM, tileN, nullptr, bn, NCLASS * DCONV, 1, out, nullptr, NCLASS * DCONV);
}

__global__ __launch_bounds__(256) void k_emb(
    const u16* __restrict__ fbf, const u16* __restrict__ hbf,
    const u16* __restrict__ W2fT, const u16* __restrict__ W2hT,
    u16* __restrict__ emb)
{
    __shared__ __align__(16) u16 As[2048], Bs[2048];
    f32x4_t z = {0.f, 0.f, 0.f, 0.f};
    f32x4_t acc[4] = {z, z, z, z};
    int tileM = blockIdx.x * 64, tileN = blockIdx.y * 64;
    mfma_tiles(fbf, 256, nullptr, W2fT, 256, tileM, tileN, As, Bs, acc);
    mfma_tiles(hbf, NCLASS * DCONV, nullptr, W2hT, NCLASS * DCONV, tileM, tileN, As, Bs, acc);
    epilogue(acc, tileM, tileN, nullptr, nullptr, 0, 1, emb, nullptr, 256);
}

__global__ __launch_bounds__(256) void k_dec(
    const u16* __restrict__ emb, const u16* __restrict__ WdecT,
    float* __restrict__ t0, float* __restrict__ t1)
{
    __shared__ __align__(16) u16 As[2048], Bs[2048];
    f32x4_t z = {0.f, 0.f, 0.f, 0.f};
    f32x4_t acc[4] = {z, z, z, z};
    int zi = blockIdx.z;
    const u16* BT = WdecT + (size_t)zi * 256 * 256;
    float* out = zi ? t1 : t0;
    int tileM = blockIdx.x * 64, tileN = blockIdx.y * 64;
    mfma_tiles(emb, 256, nullptr, BT, 256, tileM, tileN, As, Bs, acc);
    epilogue(acc, tileM, tileN, nullptr, nullptr, 0, 0, nullptr, out, 256);
}

// ============================================================================
// prep conversions
// ============================================================================
__global__ __launch_bounds__(256) void cvt_feat(
    const float* __restrict__ uf, const float* __restrict__ itf,
    u16* __restrict__ ubf, u16* __restrict__ ibf)
{
    const size_t n4 = (size_t)NUSERS * DFEAT / 4;
    for (size_t i = (size_t)blockIdx.x * 256 + threadIdx.x; i < 2 * n4;
         i += (size_t)gridDim.x * 256) {
        bool u = i < n4;
        size_t j = u ? i : i - n4;
        float4 v = u ? ((const float4*)uf)[j] : ((const float4*)itf)[j];
        ushort4 o;
        o.x = f2bf(v.x); o.y = f2bf(v.y); o.z = f2bf(v.z); o.w = f2bf(v.w);
        ((ushort4*)(u ? ubf : ibf))[j] = o;
    }
}

#define OFF_WFU   0
#define OFF_WFI   65536
#define OFF_WUC   131072
#define OFF_WIC   294912
#define OFF_W2FU  458752
#define OFF_W2HU  524288
#define OFF_W2FI  688128
#define OFF_W2HI  753664
#define OFF_WDEC  917504

__global__ __launch_bounds__(256) void cvt_wt(
    const float* __restrict__ Wfu, const float* __restrict__ Wfi,
    const float* __restrict__ Wuc, const float* __restrict__ Wic,
    const float* __restrict__ W2fu, const float* __restrict__ W2hu,
    const float* __restrict__ W2fi, const float* __restrict__ W2hi,
    const float* __restrict__ Wdec, u16* __restrict__ wT)
{
    const float* in; u16* out; int K, N, B;
    switch (blockIdx.y) {
        case 0: in = Wfu;  out = wT + OFF_WFU;  K = 256; N = 256; B = 1; break;
        case 1: in = Wfi;  out = wT + OFF_WFI;  K = 256; N = 256; B = 1; break;
        case 2: in = Wuc;  out = wT + OFF_WUC;  K = 256; N = 128; B = 5; break;
        case 3: in = Wic;  out = wT + OFF_WIC;  K = 256; N = 128; B = 5; break;
        case 4: in = W2fu; out = wT + OFF_W2FU; K = 256; N = 256; B = 1; break;
        case 5: in = W2hu; out = wT + OFF_W2HU; K = 640; N = 256; B = 1; break;
        case 6: in = W2fi; out = wT + OFF_W2FI; K = 256; N = 256; B = 1; break;
        case 7: in = W2hi; out = wT + OFF_W2HI; K = 640; N = 256; B = 1; break;
        default: in = Wdec; out = wT + OFF_WDEC; K = 256; N = 256; B = 2; break;
    }
    int total = B * K * N;
    for (int idx = blockIdx.x * 256 + threadIdx.x; idx < total; idx += gridDim.x * 256) {
        int b = idx / (K * N);
        int r = idx - b * K * N;
        int n = r / K;
        int k = r - n * K;
        out[idx] = f2bf(in[(size_t)(b * K + k) * N + n]);
    }
}

// ============================================================================
// CSR build: LDS-privatized hist -> scan -> multi-pass packed scatter
// ============================================================================
__global__ __launch_bounds__(256) void hist_kernel(
    const int* __restrict__ u_dst, const int* __restrict__ i_dst, int* __restrict__ counts)
{
    __shared__ int h[NBATCH];                    // 32 KB private histogram
    int cs = blockIdx.y;
    const int* dstp = (cs < NCLASS) ? (u_dst + (size_t)cs * NEDGE)
                                    : (i_dst + (size_t)(cs - NCLASS) * NEDGE);
    for (int i = threadIdx.x; i < NBATCH; i += 256) h[i] = 0;
    __syncthreads();
    for (int e = blockIdx.x * 256 + threadIdx.x; e < NEDGE; e += gridDim.x * 256)
        atomicAdd(&h[dstp[e]], 1);
    __syncthreads();
    for (int i = threadIdx.x; i < NBATCH; i += 256) {
        int v = h[i];
        if (v) atomicAdd(&counts[cs * NBATCH + i], v);
    }
}

__global__ __launch_bounds__(256) void scan_kernel(
    const int* __restrict__ counts, int* __restrict__ offsets, int* __restrict__ cursor)
{
    __shared__ int sums[256];
    int cs = blockIdx.x, t = threadIdx.x;
    int base = cs * NBATCH + t * 32;
    int local[32];
    int s = 0;
    #pragma unroll
    for (int i = 0; i < 32; ++i) { local[i] = s; s += counts[base + i]; }
    sums[t] = s;
    __syncthreads();
    for (int ofs = 1; ofs < 256; ofs <<= 1) {
        int v = (t >= ofs) ? sums[t - ofs] : 0;
        __syncthreads();
        sums[t] += v;
        __syncthreads();
    }
    int excl = (t == 0) ? 0 : sums[t - 1];
    #pragma unroll
    for (int i = 0; i < 32; ++i) {
        int o = excl + local[i];
        offsets[base + i] = o;
        cursor[base + i]  = o;
    }
}

// pass p (blockIdx.z) handles dst in [p*2048, (p+1)*2048): active write window
// shrinks 40MB -> 10MB so partial lines stay resident until fully written.
__global__ __launch_bounds__(256) void scatter_kernel(
    const int* __restrict__ u_src, const int* __restrict__ u_dst, const float* __restrict__ u_w,
    const int* __restrict__ i_src, const int* __restrict__ i_dst, const float* __restrict__ i_w,
    int* __restrict__ cursor, uint2* __restrict__ sorted_ew)
{
    int cs   = blockIdx.y;
    int pass = blockIdx.z;
    const int lo = pass * (NBATCH / NPASS);
    const int hi = lo + (NBATCH / NPASS);
    const int* srcp; const int* dstp; const float* wp;
    if (cs < NCLASS) {
        srcp = u_src + (size_t)cs * NEDGE;
        dstp = u_dst + (size_t)cs * NEDGE;
        wp   = u_w   + (size_t)cs * NEDGE;
    } else {
        int c = cs - NCLASS;
        srcp = i_src + (size_t)c * NEDGE;
        dstp = i_dst + (size_t)c * NEDGE;
        wp   = i_w   + (size_t)c * NEDGE;
    }
    int*   cur = cursor + cs * NBATCH;
    uint2* out = sorted_ew + (size_t)cs * NEDGE;
    for (int e = blockIdx.x * 256 + threadIdx.x; e < NEDGE; e += gridDim.x * 256) {
        int dst = dstp[e];
        if (dst >= lo && dst < hi) {
            int pos = atomicAdd(&cur[dst], 1);
            out[pos] = make_uint2((unsigned)srcp[e], __float_as_uint(wp[e]));
        }
    }
}

// one wave per (class-side, row); lane covers 4 cols; bf16 rows (512 B/edge)
__global__ __launch_bounds__(256) void spmm_kernel(
    const u16* __restrict__ item_bf, const u16* __restrict__ user_bf,
    const uint2* __restrict__ sorted_ew,
    const int* __restrict__ offsets, const int* __restrict__ counts,
    u16* __restrict__ agg)
{
    int wave = threadIdx.x >> 6;
    int lane = threadIdx.x & 63;
    int r  = blockIdx.x * 4 + wave;
    int cs = blockIdx.y;
    const u16* feat = (cs < NCLASS) ? item_bf : user_bf;
    int off = offsets[cs * NBATCH + r];
    int cnt = counts [cs * NBATCH + r];
    const uint2* ew = sorted_ew + (size_t)cs * NEDGE + off;

    float4 acc = make_float4(0.f, 0.f, 0.f, 0.f);
    int e = 0;
    for (; e + 3 < cnt; e += 4) {
        uint2 e0 = ew[e], e1 = ew[e + 1], e2 = ew[e + 2], e3 = ew[e + 3];
        float w0 = __uint_as_float(e0.y), w1 = __uint_as_float(e1.y);
        float w2 = __uint_as_float(e2.y), w3 = __uint_as_float(e3.y);
        ushort4 v0 = *(const ushort4*)&feat[(size_t)e0.x * DFEAT + lane * 4];
        ushort4 v1 = *(const ushort4*)&feat[(size_t)e1.x * DFEAT + lane * 4];
        ushort4 v2 = *(const ushort4*)&feat[(size_t)e2.x * DFEAT + lane * 4];
        ushort4 v3 = *(const ushort4*)&feat[(size_t)e3.x * DFEAT + lane * 4];
        acc.x += w0 * bf2f(v0.x) + w1 * bf2f(v1.x) + w2 * bf2f(v2.x) + w3 * bf2f(v3.x);
        acc.y += w0 * bf2f(v0.y) + w1 * bf2f(v1.y) + w2 * bf2f(v2.y) + w3 * bf2f(v3.y);
        acc.z += w0 * bf2f(v0.z) + w1 * bf2f(v1.z) + w2 * bf2f(v2.z) + w3 * bf2f(v3.z);
        acc.w += w0 * bf2f(v0.w) + w1 * bf2f(v1.w) + w2 * bf2f(v2.w) + w3 * bf2f(v3.w);
    }
    for (; e < cnt; ++e) {
        uint2 e0 = ew[e];
        float w0 = __uint_as_float(e0.y);
        ushort4 v0 = *(const ushort4*)&feat[(size_t)e0.x * DFEAT + lane * 4];
        acc.x += w0 * bf2f(v0.x);
        acc.y += w0 * bf2f(v0.y);
        acc.z += w0 * bf2f(v0.z);
        acc.w += w0 * bf2f(v0.w);
    }
    ushort4 o;
    o.x = f2bf(acc.x); o.y = f2bf(acc.y); o.z = f2bf(acc.z); o.w = f2bf(acc.w);
    *(ushort4*)&agg[((size_t)cs * NBATCH + r) * DFEAT + lane * 4] = o;
}

__global__ __launch_bounds__(256) void decoder_kernel(
    const float* __restrict__ t0, const float* __restrict__ t1,
    const u16* __restrict__ item_emb, const float* __restrict__ Wcomb,
    float* __restrict__ out)
{
    int wave = threadIdx.x >> 6;
    int lane = threadIdx.x & 63;
    int b = blockIdx.x * 4 + wave;
    const u16*   ie = item_emb + (size_t)b * 256;
    const float* p0 = t0 + (size_t)b * 256;
    const float* p1 = t1 + (size_t)b * 256;
    float s0 = 0.f, s1 = 0.f;
    #pragma unroll
    for (int j = lane; j < 256; j += 64) {
        float v = bf2f(ie[j]);
        s0 += p0[j] * v;
        s1 += p1[j] * v;
    }
    #pragma unroll
    for (int o = 32; o > 0; o >>= 1) {
        s0 += __shfl_down(s0, o);
        s1 += __shfl_down(s1, o);
    }
    if (lane == 0) {
        #pragma unroll
        for (int r = 0; r < NCLASS; ++r)
            out[b * NCLASS + r] = Wcomb[r * 2 + 0] * s0 + Wcomb[r * 2 + 1] * s1;
    }
}

// ============================================================================
// launch
// ============================================================================
extern "C" void kernel_launch(void* const* d_in, const int* in_sizes, int n_in,
                              void* d_out, int out_size, void* d_ws, size_t ws_size,
                              hipStream_t stream)
{
    const float* user_feat = (const float*)d_in[0];
    const float* item_feat = (const float*)d_in[1];
    const int*   user_idx  = (const int*)  d_in[2];
    const int*   item_idx  = (const int*)  d_in[3];
    const int*   u_src     = (const int*)  d_in[4];
    const int*   u_dst     = (const int*)  d_in[5];
    const float* u_w       = (const float*)d_in[6];
    const int*   i_src     = (const int*)  d_in[7];
    const int*   i_dst     = (const int*)  d_in[8];
    const float* i_w       = (const float*)d_in[9];
    const float* W_fu      = (const float*)d_in[10];
    const float* b_fu      = (const float*)d_in[11];
    const float* W_fi      = (const float*)d_in[12];
    const float* b_fi      = (const float*)d_in[13];
    const float* W_uc      = (const float*)d_in[14];
    const float* W_ic      = (const float*)d_in[15];
    const float* bn_fu     = (const float*)d_in[16];
    const float* bn_hu     = (const float*)d_in[17];
    const float* bn_fi     = (const float*)d_in[18];
    const float* bn_hi     = (const float*)d_in[19];
    const float* W2_fu     = (const float*)d_in[20];
    const float* W2_hu     = (const float*)d_in[21];
    const float* W2_fi     = (const float*)d_in[22];
    const float* W2_hi     = (const float*)d_in[23];
    const float* Wdec      = (const float*)d_in[24];
    const float* Wcomb     = (const float*)d_in[25];
    float* out = (float*)d_out;

    // ---- workspace layout --------------------------------------------------
    char* ws = (char*)d_ws;
    int*   counts     = (int*)  (ws + 0);            // 10*8192 i32
    int*   offsets    = (int*)  (ws + 327680);
    int*   cursor     = (int*)  (ws + 655360);
    uint2* sorted_ew  = (uint2*)(ws + 983040);       // 40 MB (dead after spmm)
    u16*   user_bf    = (u16*)  (ws + 40983040);     // 51.2 MB
    u16*   item_bf    = (u16*)  (ws + 92183040);     // 51.2 MB
    u16*   agg_bf     = (u16*)  (ws + 143383040);    // 41.9 MB (dead after hproj)
    u16*   wT         = (u16*)  (ws + 185326080);    // 2.1 MB
    // overlays on sorted region (live f-gemm..emb, after spmm):
    u16*   f_user_bf  = (u16*)  (ws + 983040);
    u16*   f_item_bf  = (u16*)  (ws + 5177344);
    u16*   h_user_bf  = (u16*)  (ws + 9371648);
    u16*   h_item_bf  = (u16*)  (ws + 19857408);
    // overlays on agg region (live emb..decoder, after hproj):
    float* t0         = (float*)(ws + 143383040);
    float* t1         = (float*)(ws + 151771648);
    u16*   user_emb   = (u16*)  (ws + 160160256);
    u16*   item_emb   = (u16*)  (ws + 164354560);

    // ---- 1. CSR build ------------------------------------------------------
    hipMemsetAsync(counts, 0, 10 * NBATCH * sizeof(int), stream);
    hist_kernel<<<dim3(32, 10), 256, 0, stream>>>(u_dst, i_dst, counts);
    scan_kernel<<<10, 256, 0, stream>>>(counts, offsets, cursor);
    scatter_kernel<<<dim3(80, 10, NPASS), 256, 0, stream>>>(
        u_src, u_dst, u_w, i_src, i_dst, i_w, cursor, sorted_ew);

    // ---- 2. prep conversions ----------------------------------------------
    cvt_feat<<<4096, 256, 0, stream>>>(user_feat, item_feat, user_bf, item_bf);
    cvt_wt<<<dim3(160, 9), 256, 0, stream>>>(W_fu, W_fi, W_uc, W_ic,
                                             W2_fu, W2_hu, W2_fi, W2_hi, Wdec, wT);

    // ---- 3. SpMM aggregation ----------------------------------------------
    spmm_kernel<<<dim3(NBATCH / 4, 10), 256, 0, stream>>>(
        item_bf, user_bf, sorted_ew, offsets, counts, agg_bf);

    // ---- 4. f path ---------------------------------------------------------
    k_gemm_f<<<dim3(128, 4), 256, 0, stream>>>(user_bf, user_idx, wT + OFF_WFU,
                                               b_fu, bn_fu, f_user_bf);
    k_gemm_f<<<dim3(128, 4), 256, 0, stream>>>(item_bf, item_idx, wT + OFF_WFI,
                                               b_fi, bn_fi, f_item_bf);

    // ---- 5. h projection ---------------------------------------------------
    k_hproj<<<dim3(128, 2, 10), 256, 0, stream>>>(agg_bf, wT + OFF_WUC, wT + OFF_WIC,
                                                  bn_hu, bn_hi, h_user_bf, h_item_bf);

    // ---- 6. embeddings ------------------------------------------------------
    k_emb<<<dim3(128, 4), 256, 0, stream>>>(f_user_bf, h_user_bf,
                                            wT + OFF_W2FU, wT + OFF_W2HU, user_emb);
    k_emb<<<dim3(128, 4), 256, 0, stream>>>(f_item_bf, h_item_bf,
                                            wT + OFF_W2FI, wT + OFF_W2HI, item_emb);

    // ---- 7. decoder ---------------------------------------------------------
    k_dec<<<dim3(128, 4, 2), 256, 0, stream>>>(user_emb, wT + OFF_WDEC, t0, t1);
    decoder_kernel<<<NBATCH / 4, 256, 0, stream>>>(t0, t1, item_emb, Wcomb, out);
}